// Round 8
// baseline (627.688 us; speedup 1.0000x reference)
//
#include <hip/hip_runtime.h>

#define S 7
#define NB 2
#define NC 80
#define NBOX 20
#define CELLS 49
#define CH 85                  // 5 + NC
#define PAIR 170               // NB*CH
#define PER_B 8330             // CELLS*PAIR floats per image
#define NIMG 4096
#define IMGS_PER_BLOCK 4
#define GRID (NIMG/IMGS_PER_BLOCK)   // 1024 blocks, 1 image per wave
#define L_COORD 5.0f
#define L_NOOBJ 0.5f
#define INV_B (1.0f/4096.0f)

// One wave per image. Lane b (<20) owns box b in registers. Per cell:
// winner via ballot, targets via shfl, 170 floats via 4 coalesced loads,
// branch-free per-lane contribution.
__global__ __launch_bounds__(256) void fused_kernel(
    const float*  __restrict__ pred,
    const float4* __restrict__ boxes4,   // [NIMG*NBOX]
    const int*    __restrict__ labels,
    float*        __restrict__ out)
{
    const int tid  = threadIdx.x;
    const int lane = tid & 63;
    const int wv   = tid >> 6;
    const int img  = blockIdx.x * IMGS_PER_BLOCK + wv;

    // per-lane box data
    float cx = 0.f, cy = 0.f, bw = 0.f, bh = 0.f;
    int myCell = -1, myLab = 0;
    if (lane < NBOX) {
        float4 bq = boxes4[img * NBOX + lane];
        cx = (bq.x + bq.z) * 0.5f; cy = (bq.y + bq.w) * 0.5f;
        bw = bq.z - bq.x;          bh = bq.w - bq.y;
        int j = min(max((int)floorf(cx * (float)S), 0), S - 1);
        int i = min(max((int)floorf(cy * (float)S), 0), S - 1);
        myCell = i * S + j;
        myLab  = labels[img * NBOX + lane];
    }

    float acc = 0.f;
    const float* pc = pred + (size_t)img * PER_B;

    #pragma unroll 2
    for (int c = 0; c < CELLS; ++c, pc += PAIR) {
        // ---- all loads upfront (both boxes, speculative) ----
        float p0a = pc[lane];                               // box0 ch 0..63
        float p0b = pc[CH + lane];                          // box1 ch 0..63
        float p1a = (lane < CH - 64) ? pc[64 + lane]      : 0.f;  // box0 ch 64..84
        float p1b = (lane < CH - 64) ? pc[CH + 64 + lane] : 0.f;  // box1 ch 64..84

        // ---- winner (min box index whose center falls in cell c) ----
        unsigned long long mask = __ballot(myCell == c);
        bool obj = (mask != 0ULL);
        int win = __ffsll(mask) - 1;
        win = (win < 0) ? 0 : win;

        float tx = __shfl(cx, win) * (float)S - (float)(c % S);
        float ty = __shfl(cy, win) * (float)S - (float)(c / S);
        float tw = __shfl(bw, win);
        float th = __shfl(bh, win);
        int  lab = __shfl(myLab, win);

        // ---- predicted box coords from the cooperative loads ----
        float px0 = __shfl(p0a, 0), py0 = __shfl(p0a, 1);
        float pw0 = __shfl(p0a, 2), ph0 = __shfl(p0a, 3);
        float px1 = __shfl(p0b, 0), py1 = __shfl(p0b, 1);
        float pw1 = __shfl(p0b, 2), ph1 = __shfl(p0b, 3);

        // ---- IoU (reference formulas), redundantly on all lanes ----
        float bx1 = tx - tw * 0.5f, by1 = ty - th * 0.5f;
        float bx2 = tx + tw * 0.5f, by2 = ty + th * 0.5f;
        float barea = (bx2 - bx1) * (by2 - by1);

        float a0x1 = px0 - pw0 * 0.5f, a0y1 = py0 - ph0 * 0.5f;
        float a0x2 = px0 + pw0 * 0.5f, a0y2 = py0 + ph0 * 0.5f;
        float iw0 = fmaxf(fminf(a0x2, bx2) - fmaxf(a0x1, bx1), 0.f);
        float ih0 = fmaxf(fminf(a0y2, by2) - fmaxf(a0y1, by1), 0.f);
        float inter0 = iw0 * ih0;
        float iou0 = inter0 / ((a0x2 - a0x1) * (a0y2 - a0y1) + barea - inter0 + 1e-6f);

        float a1x1 = px1 - pw1 * 0.5f, a1y1 = py1 - ph1 * 0.5f;
        float a1x2 = px1 + pw1 * 0.5f, a1y2 = py1 + ph1 * 0.5f;
        float iw1 = fmaxf(fminf(a1x2, bx2) - fmaxf(a1x1, bx1), 0.f);
        float ih1 = fmaxf(fminf(a1y2, by2) - fmaxf(a1y1, by1), 0.f);
        float inter1 = iw1 * ih1;
        float iou1 = inter1 / ((a1x2 - a1x1) * (a1y2 - a1y1) + barea - inter1 + 1e-6f);

        bool resp1 = (iou1 > iou0);   // argmax, first-wins tie

        // ---- per-lane contribution, branch-free ----
        // round 0: ch = lane (0..63)
        float pa = resp1 ? p0b : p0a;
        int ch = lane;
        float t = (ch >= 5) ? (((ch - 5) == lab) ? 1.f : 0.f)
                : (ch == 4) ? 1.f
                : (ch == 0) ? tx : (ch == 1) ? ty : (ch == 2) ? tw : th;
        bool issq = (ch == 2) || (ch == 3);
        float q  = issq ? sqrtf(fmaxf(pa, 1e-6f)) : pa;
        float tq = issq ? sqrtf(fmaxf(t,  1e-6f)) : t;
        float d0 = q - tq;
        float m0 = (ch < 4) ? L_COORD : 1.f;
        float objc = m0 * d0 * d0;

        // round 1: ch = 64+lane (lane<21), class channels only
        float pb = resp1 ? p1b : p1a;
        float t1 = ((59 + lane) == lab) ? 1.f : 0.f;   // ch-5 = 59+lane
        float d1 = pb - t1;
        objc += (lane < CH - 64) ? d1 * d1 : 0.f;

        // noobj: lane 4 carries 0.5*(conf0^2 + conf1^2)
        float noc = (ch == 4) ? L_NOOBJ * (p0a * p0a + p0b * p0b) : 0.f;

        acc += obj ? objc : noc;
    }

    // ---- wave reduce -> block reduce -> one atomic per block ----
    #pragma unroll
    for (int off = 32; off > 0; off >>= 1) acc += __shfl_down(acc, off, 64);
    __shared__ float s_wsum[IMGS_PER_BLOCK];
    if (lane == 0) s_wsum[wv] = acc;
    __syncthreads();
    if (tid == 0)
        atomicAdd(out, (s_wsum[0] + s_wsum[1] + s_wsum[2] + s_wsum[3]) * INV_B);
}

extern "C" void kernel_launch(void* const* d_in, const int* in_sizes, int n_in,
                              void* d_out, int out_size, void* d_ws, size_t ws_size,
                              hipStream_t stream) {
    const float*  pred   = (const float*)d_in[0];
    const float4* boxes4 = (const float4*)d_in[1];
    const int*    labels = (const int*)d_in[2];
    float* out = (float*)d_out;

    // d_out is re-poisoned to 0xAA before every replay — zero it on-stream.
    hipMemsetAsync(d_out, 0, sizeof(float) * out_size, stream);
    fused_kernel<<<GRID, 256, 0, stream>>>(pred, boxes4, labels, out);
}

// Round 9
// 204.331 us; speedup vs baseline: 3.0719x; 3.0719x over previous
//
#include <hip/hip_runtime.h>

#define S 7
#define NB 2
#define NC 80
#define NBOX 20
#define CELLS 49
#define CH 85                  // 5 + NC
#define PAIR 170               // NB*CH
#define PER_B 8330             // CELLS*PAIR floats per image
#define NIMG 4096
#define NCELL_TOT (NIMG*CELLS)           // 200704 cells
#define NBOXSLOT (NIMG*CELLS*NB)         // 401408 (cell,box) weight slots
#define N4TOT (NIMG*PER_B/4)             // 8529920 float4s
#define PREP_IMGS 4
#define PREP_BLOCKS (NIMG/PREP_IMGS)     // 1024
#define STREAM_BLOCKS 1960               // 1960*256*17 == N4TOT exactly (no tail)
#define STREAM_ITERS 17
#define WB_LDS 212                       // boxes spanned per block (<=206) + slack
#define L_COORD 5.0f
#define L_NOOBJ 0.5f

typedef float vfloat4 __attribute__((ext_vector_type(4)));

// ---------------- block reduce helper (256 threads) ----------------
__device__ __forceinline__ void block_reduce_store(float acc, float* dst)
{
    __shared__ float s_wsum[4];
    int tid = threadIdx.x;
    #pragma unroll
    for (int off = 32; off > 0; off >>= 1) acc += __shfl_down(acc, off, 64);
    int lane = tid & 63, wv = tid >> 6;
    if (lane == 0) s_wsum[wv] = acc;
    __syncthreads();
    if (tid == 0) *dst = s_wsum[0] + s_wsum[1] + s_wsum[2] + s_wsum[3];
}

// ---- kernel 1: per-(cell,box) scalar weight wb ∈ {0,1} + all corrections ----
// Stream computes sum wb * p^2 over ALL 85 channels of each box. Prep folds in:
//   obj cell, resp box:  xy/wh full terms, conf (1-2p), class (1-2p_label),
//                        MINUS the raw p^2 of channels 0..3 (streamed at w=1).
//   noobj cell:          the 0.5*(p4^2 + p89^2) conf terms directly (wb = 0).
__global__ __launch_bounds__(256) void prep_kernel(
    const float* __restrict__ pred,
    const float* __restrict__ boxes,
    const int*   __restrict__ labels,
    float*       __restrict__ wb,       // [NBOXSLOT + pad]
    float*       __restrict__ partial)  // [PREP_BLOCKS]
{
    __shared__ int   s_winner[PREP_IMGS * CELLS];
    __shared__ float s_cx[PREP_IMGS * NBOX], s_cy[PREP_IMGS * NBOX];
    __shared__ float s_bw[PREP_IMGS * NBOX], s_bh[PREP_IMGS * NBOX];
    __shared__ int   s_lab[PREP_IMGS * NBOX];

    const int b0  = blockIdx.x * PREP_IMGS;
    const int tid = threadIdx.x;

    if (tid < PREP_IMGS * CELLS) s_winner[tid] = NBOX;
    __syncthreads();

    // Phase A: 80 boxes (4 images) -> cells, winner = min box index per cell
    if (tid < PREP_IMGS * NBOX) {
        int img = tid / NBOX, bxi = tid - img * NBOX;
        const float* bx = boxes + ((size_t)(b0 + img) * NBOX + bxi) * 4;
        float x1 = bx[0], y1 = bx[1], x2 = bx[2], y2 = bx[3];
        float x = (x1 + x2) * 0.5f, y = (y1 + y2) * 0.5f;
        s_cx[tid] = x; s_cy[tid] = y;
        s_bw[tid] = x2 - x1; s_bh[tid] = y2 - y1;
        s_lab[tid] = labels[(size_t)(b0 + img) * NBOX + bxi];
        int j = (int)floorf(x * (float)S); j = min(max(j, 0), S - 1);
        int i = (int)floorf(y * (float)S); i = min(max(i, 0), S - 1);
        atomicMin(&s_winner[img * CELLS + i * S + j], bxi);
    }
    __syncthreads();

    // Phase B: per-cell responsible box, weights, corrections
    float acc = 0.0f;
    if (tid < PREP_IMGS * CELLS) {
        int img  = tid / CELLS;
        int cell = tid - img * CELLS;
        int w    = s_winner[tid];
        size_t slot = ((size_t)(b0 + img) * CELLS + cell) * 2;
        const float* p = pred + ((size_t)(b0 + img) * CELLS + cell) * PAIR;
        float w0 = 0.f, w1 = 0.f;
        if (w < NBOX) {
            int i = cell / S, j = cell - (cell / S) * S;
            int bi = img * NBOX + w;
            float x = s_cx[bi], y = s_cy[bi];
            float tx = x * (float)S - (float)j;
            float ty = y * (float)S - (float)i;
            float tw = s_bw[bi], th = s_bh[bi];

            float bx1 = tx - tw * 0.5f, by1 = ty - th * 0.5f;
            float bx2 = tx + tw * 0.5f, by2 = ty + th * 0.5f;
            float barea = (bx2 - bx1) * (by2 - by1);
            float iou[2], px[2], py[2], pw[2], ph[2];
            #pragma unroll
            for (int nb = 0; nb < NB; nb++) {
                px[nb] = p[nb * CH + 0]; py[nb] = p[nb * CH + 1];
                pw[nb] = p[nb * CH + 2]; ph[nb] = p[nb * CH + 3];
                float ax1 = px[nb] - pw[nb] * 0.5f, ay1 = py[nb] - ph[nb] * 0.5f;
                float ax2 = px[nb] + pw[nb] * 0.5f, ay2 = py[nb] + ph[nb] * 0.5f;
                float iw = fmaxf(fminf(ax2, bx2) - fmaxf(ax1, bx1), 0.0f);
                float ih = fmaxf(fminf(ay2, by2) - fmaxf(ay1, by1), 0.0f);
                float inter = iw * ih;
                float uni = (ax2 - ax1) * (ay2 - ay1) + barea - inter;
                iou[nb] = inter / (uni + 1e-6f);
            }
            int resp = (iou[1] > iou[0]) ? 1 : 0;
            w0 = (resp == 0) ? 1.f : 0.f;
            w1 = 1.f - w0;

            float pc = p[resp * CH + 4];
            float pl = p[resp * CH + 5 + s_lab[bi]];
            float dx = px[resp] - tx, dy = py[resp] - ty;
            float dw = sqrtf(fmaxf(pw[resp], 1e-6f)) - sqrtf(fmaxf(tw, 1e-6f));
            float dh = sqrtf(fmaxf(ph[resp], 1e-6f)) - sqrtf(fmaxf(th, 1e-6f));
            acc = L_COORD * (dx * dx + dy * dy + dw * dw + dh * dh)
                + (1.0f - 2.0f * pc)         // (p-1)^2 = p^2 + (1-2p)
                + (1.0f - 2.0f * pl)         // sum(p-onehot)^2 = sum p^2 + (1-2p_l)
                - (px[resp] * px[resp] + py[resp] * py[resp]
                 + pw[resp] * pw[resp] + ph[resp] * ph[resp]);  // streamed at w=1
        } else {
            float c0 = p[4], c1 = p[CH + 4];
            acc = L_NOOBJ * (c0 * c0 + c1 * c1);   // wb stays 0 for both boxes
        }
        wb[slot]     = w0;
        wb[slot + 1] = w1;
    }
    __syncthreads();
    block_reduce_store(acc, &partial[blockIdx.x]);
}

// ---- kernel 2: pure stream, acc += wb[box] * p^2, weights cached in LDS ----
// A block covers 17408 contiguous floats = ~205 boxes. One coalesced LDS fill
// turns the per-iter weight fetch into LDS reads: 1 vmem instr per 16B payload
// instead of 3 (attacking the vmem-issue-rate bound).
__global__ __launch_bounds__(256) void stream_kernel(
    const vfloat4* __restrict__ p4,
    const float*   __restrict__ wb,
    float*         __restrict__ partial)   // [STREAM_BLOCKS]
{
    __shared__ float s_wb[WB_LDS];
    const int tid  = threadIdx.x;
    const int base = blockIdx.x * (STREAM_ITERS * 256);
    const unsigned B0 = (4u * (unsigned)base) / 85u;   // first box this block touches

    if (tid < WB_LDS) s_wb[tid] = wb[B0 + tid];        // ws pad keeps this in-bounds
    __syncthreads();

    float acc = 0.0f;
    #pragma unroll
    for (int k = 0; k < STREAM_ITERS; ++k) {
        int e = base + k * 256 + tid;
        vfloat4 v = p4[e];
        unsigned ff = 4u * (unsigned)e;
        unsigned bi = ff / 85u;                 // magic-mul
        int r85 = (int)(ff - bi * 85u);
        int thr = 85 - r85;                     // element k uses next box iff k >= thr
        unsigned li = bi - B0;
        float wa = s_wb[li];
        float wn = s_wb[li + 1];
        float w1 = (1 < thr) ? wa : wn;
        float w2 = (2 < thr) ? wa : wn;
        float w3 = (3 < thr) ? wa : wn;
        acc += wa * (v.x * v.x);
        acc += w1 * (v.y * v.y);
        acc += w2 * (v.z * v.z);
        acc += w3 * (v.w * v.w);
    }
    block_reduce_store(acc, &partial[blockIdx.x]);
}

// ---------------- kernel 3: final reduce ----------------
__global__ __launch_bounds__(256) void reduce_kernel(
    const float* __restrict__ partial, int n,
    float* __restrict__ out, float inv_B)
{
    const int tid = threadIdx.x;
    float acc = 0.0f;
    for (int i = tid; i < n; i += 256) acc += partial[i];
    __shared__ float s_wsum[4];
    #pragma unroll
    for (int off = 32; off > 0; off >>= 1) acc += __shfl_down(acc, off, 64);
    int lane = tid & 63, wv = tid >> 6;
    if (lane == 0) s_wsum[wv] = acc;
    __syncthreads();
    if (tid == 0) out[0] = (s_wsum[0] + s_wsum[1] + s_wsum[2] + s_wsum[3]) * inv_B;
}

extern "C" void kernel_launch(void* const* d_in, const int* in_sizes, int n_in,
                              void* d_out, int out_size, void* d_ws, size_t ws_size,
                              hipStream_t stream) {
    const float* pred   = (const float*)d_in[0];
    const float* boxes  = (const float*)d_in[1];
    const int*   labels = (const int*)d_in[2];

    // workspace layout (floats): [wb table (+pad for LDS fill) | prep partials | stream partials]
    float* wb          = (float*)d_ws;
    float* prep_part   = wb + NBOXSLOT + WB_LDS + 16;
    float* stream_part = prep_part + PREP_BLOCKS;

    prep_kernel<<<PREP_BLOCKS, 256, 0, stream>>>(pred, boxes, labels, wb, prep_part);
    stream_kernel<<<STREAM_BLOCKS, 256, 0, stream>>>((const vfloat4*)pred, wb, stream_part);
    reduce_kernel<<<1, 256, 0, stream>>>(prep_part, PREP_BLOCKS + STREAM_BLOCKS,
                                         (float*)d_out, 1.0f / (float)NIMG);
}